// Round 21
// baseline (344.628 us; speedup 1.0000x reference)
//
#include <hip/hip_runtime.h>
#include <stdint.h>
#include <stddef.h>

#define C_DIM 248
#define N_KP 512
#define HW_PIX 65536
#define NWIN 4
#define NU 8                 // kp eighths (4 tiles = 32 KB each)
#define GROUPS128 512        // 128-px groups per window (merged partials)
#define SCALE_LOG2 144.2695041f   // 100 * log2(e)

typedef __attribute__((ext_vector_type(8))) _Float16 f16x8;
typedef __attribute__((ext_vector_type(4))) float f32x4;

__device__ __forceinline__ float fexp2(float x) {
    return __builtin_amdgcn_exp2f(x);
}

// ---------- Kernel 1: kp desc -> tile-contiguous f16 fragments ----------
// Bws[(b*32+t)*512 + kk*64 + l4*16 + c15] = 8 f16 for k = kk*32+l4*8+j, col = t*16+c15
__global__ __launch_bounds__(256) void k_prep(const float* __restrict__ kd,
                                              f16x8* __restrict__ Bws) {
    int g = blockIdx.x * 256 + threadIdx.x;       // 65536 threads
    int c15 = g & 15;
    int l4 = (g >> 4) & 3;
    int kk = (g >> 6) & 7;
    int t  = (g >> 9) & 31;
    int b  = g >> 14;
    int col = t * 16 + c15;
    const float* base = kd + (size_t)(2 * b + 1) * C_DIM * N_KP;
    f16x8 hv;
    #pragma unroll
    for (int j = 0; j < 8; ++j) {
        int c = kk * 32 + l4 * 8 + j;
        float v = (c < C_DIM) ? base[(size_t)c * N_KP + col] : 0.0f;
        hv[j] = (_Float16)v;
    }
    Bws[(size_t)(b * 32 + t) * 512 + kk * 64 + l4 * 16 + c15] = hv;
}

// ---------- Kernel 2: 4-wave blocks, B-eighths resident, 2 blocks/CU ----------
// grid: 4 win x 512 groups (128 px); block 256 = 4 waves x 32 px; 68 KB LDS
__global__ void k_main(const float* __restrict__ dd,
                       const f16x8* __restrict__ Bws,
                       float4* __restrict__ partials) {
    int b = blockIdx.x >> 9;
    int grp = blockIdx.x & 511;
    int tid = threadIdx.x;
    int lane = tid & 63;
    int wave = tid >> 6;
    int l15 = lane & 15;
    int l4 = lane >> 4;
    int pw = grp * 128 + wave * 32;               // this wave's first pixel

    __shared__ __align__(16) short Bbuf[2][16384];  // 2 x 32 KB kp-eighth buffers
    __shared__ float4 Wst[4][4][16];                // 4 KB: [wave][tile-slot][kp15]

    const f16x8* Bwin = Bws + (size_t)b * 32 * 512;
    // stage one 32 KB eighth (2048 frags) with 256 threads x 8 loads of 16 B
    #define STAGE(slot_, u_)                                                          \
        {                                                                             \
            const f16x8* src_ = Bwin + (size_t)(u_) * 2048;                           \
            _Pragma("unroll")                                                         \
            for (int i_ = 0; i_ < 8; ++i_) {                                          \
                __builtin_amdgcn_global_load_lds(                                     \
                    (const __attribute__((address_space(1))) void*)                   \
                        (src_ + i_ * 256 + tid),                                      \
                    (__attribute__((address_space(3))) void*)                         \
                        ((char*)&Bbuf[slot_][0] + (i_ * 256 + tid) * 16),             \
                    16, 0, 0);                                                        \
            }                                                                         \
        }

    STAGE(0, 0)

    // ---- A: 32 px x 256 k per wave in f16 regs, fused norm (hides stage latency) ----
    const float* srcp = dd + (size_t)(2 * b) * C_DIM * HW_PIX;
    f16x8 aH[2][8];
    float ss[2] = {0.f, 0.f};
    #pragma unroll
    for (int s = 0; s < 2; ++s) {
        #pragma unroll
        for (int kk = 0; kk < 8; ++kk) {
            #pragma unroll
            for (int j = 0; j < 8; ++j) {
                int c = kk * 32 + l4 * 8 + j;
                float v = (c < C_DIM) ? srcp[(size_t)c * HW_PIX + pw + s * 16 + l15] : 0.0f;
                ss[s] = fmaf(v, v, ss[s]);
                aH[s][kk][j] = (_Float16)v;
            }
        }
        ss[s] += __shfl_xor(ss[s], 16);
        ss[s] += __shfl_xor(ss[s], 32);           // full 248-sum for pixel pw+s*16+l15
    }
    float srow[2][4];
    #pragma unroll
    for (int s = 0; s < 2; ++s) {
        #pragma unroll
        for (int r = 0; r < 4; ++r) {
            float ssr = __shfl(ss[s], l4 * 4 + r);
            srow[s][r] = SCALE_LOG2 / fmaxf(sqrtf(ssr), 1e-12f);
        }
    }
    float ubase = (float)((pw & 255) + l4 * 4);

    // prologue rendezvous: stage(0) + A loads drained once
    asm volatile("s_waitcnt vmcnt(0)" ::: "memory");
    __builtin_amdgcn_s_barrier();

    for (int u = 0; u < NU; ++u) {
        if (u + 1 < NU) STAGE((u + 1) & 1, u + 1)   // 8 loads into the other buffer

        const short* qbase = &Bbuf[u & 1][0];
        #pragma unroll 2
        for (int tt = 0; tt < 4; ++tt) {            // free-running: no syncs inside
            const f16x8* Bt = (const f16x8*)(qbase + tt * 4096);
            f32x4 acc[2][2];
            #pragma unroll
            for (int s = 0; s < 2; ++s)
                #pragma unroll
                for (int qq = 0; qq < 2; ++qq) acc[s][qq] = (f32x4){0.f, 0.f, 0.f, 0.f};

            __builtin_amdgcn_s_setprio(1);
            #pragma unroll
            for (int kp = 0; kp < 4; ++kp) {        // 4 chains x 4 MFMA
                f16x8 b0 = Bt[(2 * kp) * 64 + lane];
                f16x8 b1 = Bt[(2 * kp + 1) * 64 + lane];
                acc[0][0] = __builtin_amdgcn_mfma_f32_16x16x32_f16(aH[0][2 * kp], b0, acc[0][0], 0, 0, 0);
                acc[1][0] = __builtin_amdgcn_mfma_f32_16x16x32_f16(aH[1][2 * kp], b0, acc[1][0], 0, 0, 0);
                acc[0][1] = __builtin_amdgcn_mfma_f32_16x16x32_f16(aH[0][2 * kp + 1], b1, acc[0][1], 0, 0, 0);
                acc[1][1] = __builtin_amdgcn_mfma_f32_16x16x32_f16(aH[1][2 * kp + 1], b1, acc[1][1], 0, 0, 0);
            }
            __builtin_amdgcn_s_setprio(0);

            // per-lane softmax partial over its 8 px rows (kp col = (u*4+tt)*16+l15)
            float lg[2][4];
            float m = -3.0e38f;
            #pragma unroll
            for (int s = 0; s < 2; ++s)
                #pragma unroll
                for (int r = 0; r < 4; ++r) {
                    lg[s][r] = (acc[s][0][r] + acc[s][1][r]) * srow[s][r];
                    m = fmaxf(m, lg[s][r]);
                }
            float d = 0.f, sx = 0.f;
            #pragma unroll
            for (int s = 0; s < 2; ++s)
                #pragma unroll
                for (int r = 0; r < 4; ++r) {
                    float e = fexp2(lg[s][r] - m);
                    d += e;
                    sx = fmaf(e, ubase + (float)(s * 16 + r), sx);
                }
            #pragma unroll
            for (int off = 16; off <= 32; off <<= 1) {  // merge the 4 l4 row-groups
                float m2 = __shfl_xor(m, off);
                float d2 = __shfl_xor(d, off);
                float sx2 = __shfl_xor(sx, off);
                float Mn = fmaxf(m, m2);
                float c1 = fexp2(m - Mn);
                float c2 = fexp2(m2 - Mn);
                d  = d * c1 + d2 * c2;
                sx = sx * c1 + sx2 * c2;
                m = Mn;
            }
            if (lane < 16) {                        // per-wave partial -> LDS
                float4 p; p.x = m; p.y = d; p.z = sx; p.w = 0.f;
                Wst[wave][tt][l15] = p;
            }
        }

        // eighth boundary: own stage(u+1) loads landed + Wst writes visible
        asm volatile("s_waitcnt vmcnt(0) lgkmcnt(0)" ::: "memory");
        __builtin_amdgcn_s_barrier();
        if (tid < 64) {                             // merge 4 waves' 128-px partials
            int tslot = tid >> 4;
            int kp15 = tid & 15;
            float4 s0 = Wst[0][tslot][kp15];
            float M = s0.x, D = s0.y, SX = s0.z;
            #pragma unroll
            for (int w = 1; w < 4; ++w) {
                float4 p = Wst[w][tslot][kp15];
                float Mn = fmaxf(M, p.x);
                float c1 = fexp2(M - Mn);
                float c2 = fexp2(p.x - Mn);
                D  = D  * c1 + p.y * c2;
                SX = SX * c1 + p.z * c2;
                M = Mn;
            }
            float4 o; o.x = M; o.y = D; o.z = SX; o.w = 0.f;
            partials[((size_t)b * GROUPS128 + grp) * 512 + u * 64 + tid] = o;
        }
        if (u + 1 < NU) __builtin_amdgcn_s_barrier();  // Wst safe to reuse
    }
    #undef STAGE
}

// ---------- Kernel 3: reduce 512 group-partials per (b,kp); sy = v(g)*d ----------
// grid: 4 win x 64 kp-chunks of 8; block 256 = 8 kp x 32 g-slices
__global__ __launch_bounds__(256) void k_reduce(const float4* __restrict__ partials,
                                                const float* __restrict__ ksc,
                                                float* __restrict__ out) {
    int b = blockIdx.x >> 6;
    int kc = blockIdx.x & 63;
    int tid = threadIdx.x;
    int kpo = tid & 7;
    int gs = tid >> 3;
    int kp = kc * 8 + kpo;

    float M = -1e30f, D = 0.f, SX = 0.f, SY = 0.f;
    for (int g = gs; g < GROUPS128; g += 32) {
        float4 p = partials[((size_t)b * GROUPS128 + g) * 512 + kp];
        float vg = (float)(g >> 1);                 // v constant per 128-px group
        float Mn = fmaxf(M, p.x);
        float c1 = fexp2(M - Mn);
        float c2 = fexp2(p.x - Mn);
        D  = D  * c1 + p.y * c2;
        SX = SX * c1 + p.z * c2;
        SY = SY * c1 + vg * p.y * c2;
        M = Mn;
    }
    __shared__ float4 red[32][8];
    float4 me; me.x = M; me.y = D; me.z = SX; me.w = SY;
    red[gs][kpo] = me;
    __syncthreads();
    if (gs == 0) {
        #pragma unroll
        for (int w = 1; w < 32; ++w) {
            float4 p = red[w][kpo];
            float Mn = fmaxf(M, p.x);
            float c1 = fexp2(M - Mn);
            float c2 = fexp2(p.x - Mn);
            D  = D  * c1 + p.y * c2;
            SX = SX * c1 + p.z * c2;
            SY = SY * c1 + p.w * c2;
            M = Mn;
        }
        int flat = b * 512 + kp;
        out[flat * 2 + 0] = SX / D;
        out[flat * 2 + 1] = SY / D;
        out[4096 + flat] = ksc[(size_t)(2 * b + 1) * N_KP + kp];
    }
    if (blockIdx.x == 0 && tid < 4) out[6144 + tid] = (float)(2 * tid + 1);
}

extern "C" void kernel_launch(void* const* d_in, const int* in_sizes, int n_in,
                              void* d_out, int out_size, void* d_ws, size_t ws_size,
                              hipStream_t stream) {
    const float* kp_scores  = (const float*)d_in[0];
    const float* kp_desc    = (const float*)d_in[1];
    const float* desc_dense = (const float*)d_in[3];
    float* out = (float*)d_out;

    // ws: Bws 1 MB | partials 16 MB
    f16x8* Bws = (f16x8*)d_ws;
    float4* partials = (float4*)((char*)d_ws + (size_t)NWIN * 32 * 512 * 16);

    k_prep<<<256, 256, 0, stream>>>(kp_desc, Bws);
    k_main<<<NWIN * 512, 256, 0, stream>>>(desc_dense, Bws, partials);
    k_reduce<<<NWIN * 64, 256, 0, stream>>>(partials, kp_scores, out);
}

// Round 22
// 161.116 us; speedup vs baseline: 2.1390x; 2.1390x over previous
//
#include <hip/hip_runtime.h>
#include <stdint.h>
#include <stddef.h>

#define C_DIM 248
#define N_KP 512
#define HW_PIX 65536
#define NWIN 4
#define NTILE 32             // 512 kp / 16 per tile
#define NQ 4                 // kp quarters (8 tiles each)
#define GROUPS256 256        // 256-px groups per window (merged partials)
#define SCALE_LOG2 144.2695041f   // 100 * log2(e)

typedef __attribute__((ext_vector_type(8))) _Float16 f16x8;
typedef __attribute__((ext_vector_type(4))) float f32x4;

__device__ __forceinline__ float fexp2(float x) {
    return __builtin_amdgcn_exp2f(x);
}

// ---------- Kernel 1: kp desc -> tile-contiguous f16 fragments ----------
// Bws[(b*32+t)*512 + kk*64 + l4*16 + c15] = 8 f16 for k = kk*32+l4*8+j, col = t*16+c15
__global__ __launch_bounds__(256) void k_prep(const float* __restrict__ kd,
                                              f16x8* __restrict__ Bws) {
    int g = blockIdx.x * 256 + threadIdx.x;       // 65536 threads
    int c15 = g & 15;
    int l4 = (g >> 4) & 3;
    int kk = (g >> 6) & 7;
    int t  = (g >> 9) & 31;
    int b  = g >> 14;
    int col = t * 16 + c15;
    const float* base = kd + (size_t)(2 * b + 1) * C_DIM * N_KP;
    f16x8 hv;
    #pragma unroll
    for (int j = 0; j < 8; ++j) {
        int c = kk * 32 + l4 * 8 + j;
        float v = (c < C_DIM) ? base[(size_t)c * N_KP + col] : 0.0f;
        hv[j] = (_Float16)v;
    }
    Bws[(size_t)(b * 32 + t) * 512 + kk * 64 + l4 * 16 + c15] = hv;
}

// ---------- Kernel 2: B-resident quarters + in-block partial merge ----------
// grid: 4 win x 256 groups (256 px); block 512 = 8 waves x 32 px; 1 block/CU
__global__ __launch_bounds__(512, 1) void k_main(const float* __restrict__ dd,
                                                 const f16x8* __restrict__ Bws,
                                                 float4* __restrict__ partials) {
    int b = blockIdx.x >> 8;
    int grp = blockIdx.x & 255;
    int tid = threadIdx.x;
    int lane = tid & 63;
    int wave = tid >> 6;
    int l15 = lane & 15;
    int l4 = lane >> 4;
    int pw = grp * 256 + wave * 32;               // this wave's first pixel

    __shared__ __align__(16) short Bbuf[2][32768];  // 2 x 64 KB kp-quarter buffers
    __shared__ float4 Wst[8][128];                  // 16 KB: [wave][tt*16+kp15]

    const f16x8* Bwin = Bws + (size_t)b * 32 * 512;
    // stage one 64 KB quarter (4096 frags) with 512 threads x 8 loads of 16 B
    #define STAGE(slot_, q_)                                                          \
        {                                                                             \
            const f16x8* src_ = Bwin + (size_t)(q_) * 4096;                           \
            _Pragma("unroll")                                                         \
            for (int i_ = 0; i_ < 8; ++i_) {                                          \
                __builtin_amdgcn_global_load_lds(                                     \
                    (const __attribute__((address_space(1))) void*)                   \
                        (src_ + i_ * 512 + wave * 64 + lane),                         \
                    (__attribute__((address_space(3))) void*)                         \
                        ((char*)&Bbuf[slot_][0] + (i_ * 512 + wave * 64) * 16),       \
                    16, 0, 0);                                                        \
            }                                                                         \
        }

    STAGE(0, 0)

    // ---- A: 32 px x 256 k per wave in f16 regs, fused norm (hides stage latency) ----
    const float* srcp = dd + (size_t)(2 * b) * C_DIM * HW_PIX;
    f16x8 aH[2][8];
    float ss[2] = {0.f, 0.f};
    #pragma unroll
    for (int s = 0; s < 2; ++s) {
        #pragma unroll
        for (int kk = 0; kk < 8; ++kk) {
            #pragma unroll
            for (int j = 0; j < 8; ++j) {
                int c = kk * 32 + l4 * 8 + j;
                float v = (c < C_DIM) ? srcp[(size_t)c * HW_PIX + pw + s * 16 + l15] : 0.0f;
                ss[s] = fmaf(v, v, ss[s]);
                aH[s][kk][j] = (_Float16)v;
            }
        }
        ss[s] += __shfl_xor(ss[s], 16);
        ss[s] += __shfl_xor(ss[s], 32);           // full 248-sum for pixel pw+s*16+l15
    }
    float srow[2][4];
    #pragma unroll
    for (int s = 0; s < 2; ++s) {
        #pragma unroll
        for (int r = 0; r < 4; ++r) {
            float ssr = __shfl(ss[s], l4 * 4 + r);
            srow[s][r] = SCALE_LOG2 / fmaxf(sqrtf(ssr), 1e-12f);
        }
    }
    float ubase = (float)((pw & 255) + l4 * 4);

    // prologue rendezvous: stage(0) + A loads drained once
    asm volatile("s_waitcnt vmcnt(0)" ::: "memory");
    __builtin_amdgcn_s_barrier();

    for (int q = 0; q < NQ; ++q) {
        if (q + 1 < NQ) STAGE((q + 1) & 1, q + 1)   // 8 loads into the other buffer

        const short* qbase = &Bbuf[q & 1][0];
        #pragma unroll 2
        for (int tt = 0; tt < 8; ++tt) {            // free-running: no syncs inside
            const f16x8* Bt = (const f16x8*)(qbase + tt * 4096);
            f32x4 acc[2][2];
            #pragma unroll
            for (int s = 0; s < 2; ++s)
                #pragma unroll
                for (int qq = 0; qq < 2; ++qq) acc[s][qq] = (f32x4){0.f, 0.f, 0.f, 0.f};

            __builtin_amdgcn_s_setprio(1);
            #pragma unroll
            for (int kp = 0; kp < 4; ++kp) {        // 4 chains x 4 MFMA
                f16x8 b0 = Bt[(2 * kp) * 64 + lane];
                f16x8 b1 = Bt[(2 * kp + 1) * 64 + lane];
                acc[0][0] = __builtin_amdgcn_mfma_f32_16x16x32_f16(aH[0][2 * kp], b0, acc[0][0], 0, 0, 0);
                acc[1][0] = __builtin_amdgcn_mfma_f32_16x16x32_f16(aH[1][2 * kp], b0, acc[1][0], 0, 0, 0);
                acc[0][1] = __builtin_amdgcn_mfma_f32_16x16x32_f16(aH[0][2 * kp + 1], b1, acc[0][1], 0, 0, 0);
                acc[1][1] = __builtin_amdgcn_mfma_f32_16x16x32_f16(aH[1][2 * kp + 1], b1, acc[1][1], 0, 0, 0);
            }
            __builtin_amdgcn_s_setprio(0);

            // per-lane softmax partial over its 8 px rows (kp col = (q*8+tt)*16+l15)
            float lg[2][4];
            float m = -3.0e38f;
            #pragma unroll
            for (int s = 0; s < 2; ++s)
                #pragma unroll
                for (int r = 0; r < 4; ++r) {
                    lg[s][r] = (acc[s][0][r] + acc[s][1][r]) * srow[s][r];
                    m = fmaxf(m, lg[s][r]);
                }
            float d = 0.f, sx = 0.f;
            #pragma unroll
            for (int s = 0; s < 2; ++s)
                #pragma unroll
                for (int r = 0; r < 4; ++r) {
                    float e = fexp2(lg[s][r] - m);
                    d += e;
                    sx = fmaf(e, ubase + (float)(s * 16 + r), sx);
                }
            #pragma unroll
            for (int off = 16; off <= 32; off <<= 1) {  // merge the 4 l4 row-groups
                float m2 = __shfl_xor(m, off);
                float d2 = __shfl_xor(d, off);
                float sx2 = __shfl_xor(sx, off);
                float Mn = fmaxf(m, m2);
                float c1 = fexp2(m - Mn);
                float c2 = fexp2(m2 - Mn);
                d  = d * c1 + d2 * c2;
                sx = sx * c1 + sx2 * c2;
                m = Mn;
            }
            if (lane < 16) {                        // per-wave partial -> LDS
                float4 p; p.x = m; p.y = d; p.z = sx; p.w = 0.f;
                Wst[wave][tt * 16 + l15] = p;
            }
        }

        // quarter boundary: stage loads landed (issued a quarter ago -> cheap drain),
        // Wst writes visible; then 128 threads merge 8 waves' 32-px partials
        asm volatile("s_waitcnt vmcnt(0) lgkmcnt(0)" ::: "memory");
        __builtin_amdgcn_s_barrier();
        if (tid < 128) {
            float4 s0 = Wst[0][tid];
            float M = s0.x, D = s0.y, SX = s0.z;
            #pragma unroll
            for (int w = 1; w < 8; ++w) {
                float4 p = Wst[w][tid];
                float Mn = fmaxf(M, p.x);
                float c1 = fexp2(M - Mn);
                float c2 = fexp2(p.x - Mn);
                D  = D  * c1 + p.y * c2;
                SX = SX * c1 + p.z * c2;
                M = Mn;
            }
            float4 o; o.x = M; o.y = D; o.z = SX; o.w = 0.f;
            partials[((size_t)b * GROUPS256 + grp) * 512 + q * 128 + tid] = o;
        }
        if (q + 1 < NQ) __builtin_amdgcn_s_barrier();  // Wst safe to reuse
    }
    #undef STAGE
}

// ---------- Kernel 3: reduce 256 group-partials per (b,kp); sy = v(g)*d ----------
// grid: 4 win x 64 kp-chunks of 8; block 256 = 8 kp x 32 g-slices
__global__ __launch_bounds__(256) void k_reduce(const float4* __restrict__ partials,
                                                const float* __restrict__ ksc,
                                                float* __restrict__ out) {
    int b = blockIdx.x >> 6;
    int kc = blockIdx.x & 63;
    int tid = threadIdx.x;
    int kpo = tid & 7;
    int gs = tid >> 3;
    int kp = kc * 8 + kpo;

    float M = -1e30f, D = 0.f, SX = 0.f, SY = 0.f;
    for (int g = gs; g < GROUPS256; g += 32) {
        float4 p = partials[((size_t)b * GROUPS256 + g) * 512 + kp];
        float vg = (float)g;                        // 256-px group = one u-row: v = g
        float Mn = fmaxf(M, p.x);
        float c1 = fexp2(M - Mn);
        float c2 = fexp2(p.x - Mn);
        D  = D  * c1 + p.y * c2;
        SX = SX * c1 + p.z * c2;
        SY = SY * c1 + vg * p.y * c2;
        M = Mn;
    }
    __shared__ float4 red[32][8];
    float4 me; me.x = M; me.y = D; me.z = SX; me.w = SY;
    red[gs][kpo] = me;
    __syncthreads();
    if (gs == 0) {
        #pragma unroll
        for (int w = 1; w < 32; ++w) {
            float4 p = red[w][kpo];
            float Mn = fmaxf(M, p.x);
            float c1 = fexp2(M - Mn);
            float c2 = fexp2(p.x - Mn);
            D  = D  * c1 + p.y * c2;
            SX = SX * c1 + p.z * c2;
            SY = SY * c1 + p.w * c2;
            M = Mn;
        }
        int flat = b * 512 + kp;
        out[flat * 2 + 0] = SX / D;
        out[flat * 2 + 1] = SY / D;
        out[4096 + flat] = ksc[(size_t)(2 * b + 1) * N_KP + kp];
    }
    if (blockIdx.x == 0 && tid < 4) out[6144 + tid] = (float)(2 * tid + 1);
}

extern "C" void kernel_launch(void* const* d_in, const int* in_sizes, int n_in,
                              void* d_out, int out_size, void* d_ws, size_t ws_size,
                              hipStream_t stream) {
    const float* kp_scores  = (const float*)d_in[0];
    const float* kp_desc    = (const float*)d_in[1];
    const float* desc_dense = (const float*)d_in[3];
    float* out = (float*)d_out;

    // ws: Bws 1 MB | partials 8 MB
    f16x8* Bws = (f16x8*)d_ws;
    float4* partials = (float4*)((char*)d_ws + (size_t)NWIN * 32 * 512 * 16);

    k_prep<<<256, 256, 0, stream>>>(kp_desc, Bws);
    k_main<<<NWIN * 256, 512, 0, stream>>>(desc_dense, Bws, partials);
    k_reduce<<<NWIN * 64, 256, 0, stream>>>(partials, kp_scores, out);
}